// Round 2
// baseline (3293.817 us; speedup 1.0000x reference)
//
#include <hip/hip_runtime.h>

#define NB 2048
#define NT 2048
#define NH 16

#define OFF_IMP   1L
#define OFF_TRAIN (1L + (long)NB * NT)
#define OFF_EVALS (OFF_TRAIN + NB)
#define OFF_EMASK (OFF_EVALS + (long)NB * NT)

// ---------------- copies + workspace zeroing ----------------
__global__ void copy_zero_kernel(const float* __restrict__ evals,
                                 const float* __restrict__ emask,
                                 const float* __restrict__ is_train,
                                 float* __restrict__ out,
                                 float* __restrict__ numden) {
    long gid = (long)blockIdx.x * blockDim.x + threadIdx.x;
    if (gid < 2 * NT) numden[gid] = 0.0f;  // zero num[NT] + den[NT] every call
    const long n1 = (long)NB * NT;
    const long total = NB + 2 * n1;
    const long stride = (long)gridDim.x * blockDim.x;
    for (long i = gid; i < total; i += stride) {
        if (i < NB)            out[OFF_TRAIN + i] = is_train[i];
        else if (i < NB + n1)  out[OFF_EVALS + (i - NB)] = evals[i - NB];
        else                   out[OFF_EMASK + (i - NB - n1)] = emask[i - NB - n1];
    }
}

// ---------------- LSTM scan: gate-parallel, 64 lanes = 1 batch ----------------
__device__ __forceinline__ float rl(float v, int srcLane) {
    return __int_as_float(__builtin_amdgcn_readlane(__float_as_int(v), srcLane));
}

// lane = gate*16 + j  (gate order: i, f, g, o — torch LSTMCell)
__launch_bounds__(64, 2)
__global__ void lstm_kernel(const float* __restrict__ values,
                            const float* __restrict__ masks,
                            const float* __restrict__ W_ih,
                            const float* __restrict__ W_hh,
                            const float* __restrict__ b_ih,
                            const float* __restrict__ b_hh,
                            const float* __restrict__ W_reg,
                            const float* __restrict__ b_reg,
                            float* __restrict__ imp,   // out + OFF_IMP
                            float* __restrict__ num,
                            float* __restrict__ den) {
    const int lane = threadIdx.x;          // 0..63
    const int G = lane >> 4;               // gate index
    const long b = blockIdx.x;             // one batch per block/wave

    // Per-lane W_hh row (own gate row), replicated W_reg
    float Wh[NH], Wr[NH];
#pragma unroll
    for (int k = 0; k < NH; k += 4) {
        float4 v;
        v = *(const float4*)(W_hh + lane * NH + k); Wh[k]=v.x; Wh[k+1]=v.y; Wh[k+2]=v.z; Wh[k+3]=v.w;
        v = *(const float4*)(W_reg + k);            Wr[k]=v.x; Wr[k+1]=v.y; Wr[k+2]=v.z; Wr[k+3]=v.w;
    }
    const float wx0 = W_ih[lane * 2 + 0];
    const float wx1 = W_ih[lane * 2 + 1];
    const float bias = b_ih[lane] + b_hh[lane];
    const float brg = b_reg[0];

    const float L2E = 1.4426950408889634f;
    // branchless activation: gate g (G==2) -> tanh = 2*sigm(2x)-1, else sigmoid
    const float cExp = (G == 2) ? -2.0f * L2E : -L2E;
    const float sMul = (G == 2) ? 2.0f : 1.0f;
    const float sAdd = (G == 2) ? -1.0f : 0.0f;

    float h[NH];
#pragma unroll
    for (int k = 0; k < NH; ++k) h[k] = 0.0f;
    float c = 0.0f;

    const float* vb = values + b * NT;
    const float* mb = masks + b * NT;
    float* ib = imp + b * NT;

    // distance-2 chunk prefetch (8 steps ahead); all lanes load same addr -> broadcast
    float4 xcur = *(const float4*)(vb);
    float4 mcur = *(const float4*)(mb);
    float4 xnxt = *(const float4*)(vb + 4);
    float4 mnxt = *(const float4*)(mb + 4);

    for (int t4 = 0; t4 < NT; t4 += 4) {
        int tp = t4 + 8; if (tp > NT - 4) tp = NT - 4;
        float4 xpf = *(const float4*)(vb + tp);
        float4 mpf = *(const float4*)(mb + tp);

        float xi0, xi1, xi2, xi3;
#pragma unroll
        for (int s = 0; s < 4; ++s) {
            const float x = (s == 0) ? xcur.x : (s == 1) ? xcur.y : (s == 2) ? xcur.z : xcur.w;
            const float m = (s == 0) ? mcur.x : (s == 1) ? mcur.y : (s == 2) ? mcur.z : mcur.w;

            // two 16-dots as 4 parallel chains of 4 (short dep chains)
            float d0 = Wh[0] * h[0];  d0 = fmaf(Wh[1], h[1], d0);  d0 = fmaf(Wh[2], h[2], d0);  d0 = fmaf(Wh[3], h[3], d0);
            float d1 = Wh[4] * h[4];  d1 = fmaf(Wh[5], h[5], d1);  d1 = fmaf(Wh[6], h[6], d1);  d1 = fmaf(Wh[7], h[7], d1);
            float d2 = Wh[8] * h[8];  d2 = fmaf(Wh[9], h[9], d2);  d2 = fmaf(Wh[10], h[10], d2); d2 = fmaf(Wh[11], h[11], d2);
            float d3 = Wh[12] * h[12]; d3 = fmaf(Wh[13], h[13], d3); d3 = fmaf(Wh[14], h[14], d3); d3 = fmaf(Wh[15], h[15], d3);
            const float dot = (d0 + d1) + (d2 + d3);

            float r0 = Wr[0] * h[0];  r0 = fmaf(Wr[1], h[1], r0);  r0 = fmaf(Wr[2], h[2], r0);  r0 = fmaf(Wr[3], h[3], r0);
            float r1 = Wr[4] * h[4];  r1 = fmaf(Wr[5], h[5], r1);  r1 = fmaf(Wr[6], h[6], r1);  r1 = fmaf(Wr[7], h[7], r1);
            float r2 = Wr[8] * h[8];  r2 = fmaf(Wr[9], h[9], r2);  r2 = fmaf(Wr[10], h[10], r2); r2 = fmaf(Wr[11], h[11], r2);
            float r3 = Wr[12] * h[12]; r3 = fmaf(Wr[13], h[13], r3); r3 = fmaf(Wr[14], h[14], r3); r3 = fmaf(Wr[15], h[15], r3);
            const float xh = brg + ((r0 + r1) + (r2 + r3));

            const float xc = fmaf(m, x - xh, xh);       // m*x + (1-m)*xh
            const float pre = fmaf(wx1, m, bias);       // off critical path
            const float gate = fmaf(wx0, xc, dot + pre);

            // activation (branchless sigmoid/tanh)
            const float e = __builtin_amdgcn_exp2f(gate * cExp);
            const float sg = __builtin_amdgcn_rcpf(1.0f + e);
            const float act = fmaf(sMul, sg, sAdd);

            // gather f,g,o activations onto unit lanes (G==0); act there is i
            const float af = __shfl_xor(act, 16, 64);
            const float ag = __shfl_xor(act, 32, 64);
            const float ao = __shfl_xor(act, 48, 64);

            // c/h meaningful on lanes 0..15 only (others compute garbage, unused)
            c = fmaf(af, c, act * ag);
            const float e2 = __builtin_amdgcn_exp2f(c * (-2.0f * L2E));
            const float th = fmaf(2.0f, __builtin_amdgcn_rcpf(1.0f + e2), -1.0f);
            const float ht = ao * th;

            // broadcast new h from lanes 0..15 as wave-uniform scalars (no LDS, no barrier)
#pragma unroll
            for (int k = 0; k < NH; ++k) h[k] = rl(ht, k);

            if (lane == 0) {
                atomicAdd(num + t4 + s, fabsf(x - xh) * m);
                atomicAdd(den + t4 + s, m);
            }
            if (s == 0) xi0 = xc; else if (s == 1) xi1 = xc; else if (s == 2) xi2 = xc; else xi3 = xc;
        }
        // out+1 base breaks 16B alignment -> scalar dword stores by lanes 0..3
        const float iv = (lane == 0) ? xi0 : (lane == 1) ? xi1 : (lane == 2) ? xi2 : xi3;
        if (lane < 4) ib[t4 + lane] = iv;
        xcur = xnxt; mcur = mnxt; xnxt = xpf; mnxt = mpf;
    }
}

// ---------------- loss finalize ----------------
__global__ void loss_kernel(const float* __restrict__ num, const float* __restrict__ den,
                            float* __restrict__ out) {
    const int tid = threadIdx.x;
    float s = 0.0f;
    for (int t = tid; t < NT; t += 256) s += num[t] / (den[t] + 1e-5f);
#pragma unroll
    for (int off = 32; off > 0; off >>= 1) s += __shfl_down(s, off, 64);
    __shared__ float red[4];
    if ((tid & 63) == 0) red[tid >> 6] = s;
    __syncthreads();
    if (tid == 0) out[0] = (red[0] + red[1] + red[2] + red[3]) / (float)NT;
}

extern "C" void kernel_launch(void* const* d_in, const int* in_sizes, int n_in,
                              void* d_out, int out_size, void* d_ws, size_t ws_size,
                              hipStream_t stream) {
    const float* values  = (const float*)d_in[0];
    const float* masks   = (const float*)d_in[1];
    const float* evals   = (const float*)d_in[2];
    const float* emask   = (const float*)d_in[3];
    const float* istrain = (const float*)d_in[4];
    const float* W_ih    = (const float*)d_in[5];
    const float* W_hh    = (const float*)d_in[6];
    const float* b_ih    = (const float*)d_in[7];
    const float* b_hh    = (const float*)d_in[8];
    const float* W_reg   = (const float*)d_in[9];
    const float* b_reg   = (const float*)d_in[10];

    float* out = (float*)d_out;
    float* num = (float*)d_ws;       // NT floats
    float* den = num + NT;           // NT floats

    copy_zero_kernel<<<1024, 256, 0, stream>>>(evals, emask, istrain, out, num);
    lstm_kernel<<<NB, 64, 0, stream>>>(values, masks, W_ih, W_hh, b_ih, b_hh,
                                       W_reg, b_reg, out + OFF_IMP, num, den);
    loss_kernel<<<1, 256, 0, stream>>>(num, den, out);
}

// Round 3
// 718.420 us; speedup vs baseline: 4.5848x; 4.5848x over previous
//
#include <hip/hip_runtime.h>

#define NB 2048
#define NT 2048
#define NH 16

#define OFF_IMP   1L
#define OFF_TRAIN (1L + (long)NB * NT)
#define OFF_EVALS (OFF_TRAIN + NB)
#define OFF_EMASK (OFF_EVALS + (long)NB * NT)

// ws layout: num_t[NT] | den_t[NT] | amt[NB*NT] (path A)  or  rep[64*NT] (path B)
#define WS_AMT_OFF 4096
#define NREP 64

// ---------------- copies + workspace zeroing ----------------
__global__ void copy_zero_kernel(const float* __restrict__ evals,
                                 const float* __restrict__ emask,
                                 const float* __restrict__ is_train,
                                 float* __restrict__ out,
                                 float* __restrict__ ws,
                                 int n_zero) {
    long gid = (long)blockIdx.x * blockDim.x + threadIdx.x;
    if (gid < n_zero) ws[gid] = 0.0f;
    const long n1 = (long)NB * NT;
    const long total = NB + 2 * n1;
    const long stride = (long)gridDim.x * blockDim.x;
    for (long i = gid; i < total; i += stride) {
        if (i < NB)            out[OFF_TRAIN + i] = is_train[i];
        else if (i < NB + n1)  out[OFF_EVALS + (i - NB)] = evals[i - NB];
        else                   out[OFF_EMASK + (i - NB - n1)] = emask[i - NB - n1];
    }
}

// ---------------- LSTM scan: gate-parallel, 64 lanes = 1 batch ----------------
__device__ __forceinline__ float rl(float v, int srcLane) {
    return __int_as_float(__builtin_amdgcn_readlane(__float_as_int(v), srcLane));
}

// lane = gate*16 + j  (gate order: i, f, g, o — torch LSTMCell)
template <int ATOMIC>
__global__ __launch_bounds__(64, 2)
void lstm_kernel(const float* __restrict__ values,
                 const float* __restrict__ masks,
                 const float* __restrict__ W_ih,
                 const float* __restrict__ W_hh,
                 const float* __restrict__ b_ih,
                 const float* __restrict__ b_hh,
                 const float* __restrict__ W_reg,
                 const float* __restrict__ b_reg,
                 float* __restrict__ imp,   // out + OFF_IMP
                 float* __restrict__ amt) { // A: amt[NB*NT]; B: rep[NREP*NT]
    const int lane = threadIdx.x;          // 0..63
    const int G = lane >> 4;               // gate index
    const long b = blockIdx.x;             // one batch per block/wave

    float Wh[NH], Wr[NH];
#pragma unroll
    for (int k = 0; k < NH; k += 4) {
        float4 v;
        v = *(const float4*)(W_hh + lane * NH + k); Wh[k]=v.x; Wh[k+1]=v.y; Wh[k+2]=v.z; Wh[k+3]=v.w;
        v = *(const float4*)(W_reg + k);            Wr[k]=v.x; Wr[k+1]=v.y; Wr[k+2]=v.z; Wr[k+3]=v.w;
    }
    const float wx0 = W_ih[lane * 2 + 0];
    const float wx1 = W_ih[lane * 2 + 1];
    const float bias = b_ih[lane] + b_hh[lane];
    const float brg = b_reg[0];

    const float L2E = 1.4426950408889634f;
    const float cExp = (G == 2) ? -2.0f * L2E : -L2E;
    const float sMul = (G == 2) ? 2.0f : 1.0f;
    const float sAdd = (G == 2) ? -1.0f : 0.0f;

    float h[NH];
#pragma unroll
    for (int k = 0; k < NH; ++k) h[k] = 0.0f;
    float c = 0.0f;

    const float* vb = values + b * NT;
    const float* mb = masks + b * NT;
    float* ib = imp + b * NT;
    float* ab = ATOMIC ? (amt + (long)(b & (NREP - 1)) * NT) : (amt + b * NT);

    // distance-3 chunk prefetch (12 steps ahead); all lanes same addr -> broadcast
    float4 x0 = *(const float4*)(vb + 0), m0 = *(const float4*)(mb + 0);
    float4 x1 = *(const float4*)(vb + 4), m1 = *(const float4*)(mb + 4);
    float4 x2 = *(const float4*)(vb + 8), m2 = *(const float4*)(mb + 8);

    for (int t4 = 0; t4 < NT; t4 += 4) {
        int tp = t4 + 12; if (tp > NT - 4) tp = NT - 4;
        float4 xpf = *(const float4*)(vb + tp);
        float4 mpf = *(const float4*)(mb + tp);

        float xi0, xi1, xi2, xi3;   // imputations for s=0..3
        float ai0, ai1, ai2, ai3;   // |x-xh|*m for s=0..3
#pragma unroll
        for (int s = 0; s < 4; ++s) {
            const float x = (s == 0) ? x0.x : (s == 1) ? x0.y : (s == 2) ? x0.z : x0.w;
            const float m = (s == 0) ? m0.x : (s == 1) ? m0.y : (s == 2) ? m0.z : m0.w;

            // two 16-dots as 4 parallel chains of 4
            float d0 = Wh[0] * h[0];  d0 = fmaf(Wh[1], h[1], d0);  d0 = fmaf(Wh[2], h[2], d0);  d0 = fmaf(Wh[3], h[3], d0);
            float d1 = Wh[4] * h[4];  d1 = fmaf(Wh[5], h[5], d1);  d1 = fmaf(Wh[6], h[6], d1);  d1 = fmaf(Wh[7], h[7], d1);
            float d2 = Wh[8] * h[8];  d2 = fmaf(Wh[9], h[9], d2);  d2 = fmaf(Wh[10], h[10], d2); d2 = fmaf(Wh[11], h[11], d2);
            float d3 = Wh[12] * h[12]; d3 = fmaf(Wh[13], h[13], d3); d3 = fmaf(Wh[14], h[14], d3); d3 = fmaf(Wh[15], h[15], d3);
            const float dot = (d0 + d1) + (d2 + d3);

            float r0 = Wr[0] * h[0];  r0 = fmaf(Wr[1], h[1], r0);  r0 = fmaf(Wr[2], h[2], r0);  r0 = fmaf(Wr[3], h[3], r0);
            float r1 = Wr[4] * h[4];  r1 = fmaf(Wr[5], h[5], r1);  r1 = fmaf(Wr[6], h[6], r1);  r1 = fmaf(Wr[7], h[7], r1);
            float r2 = Wr[8] * h[8];  r2 = fmaf(Wr[9], h[9], r2);  r2 = fmaf(Wr[10], h[10], r2); r2 = fmaf(Wr[11], h[11], r2);
            float r3 = Wr[12] * h[12]; r3 = fmaf(Wr[13], h[13], r3); r3 = fmaf(Wr[14], h[14], r3); r3 = fmaf(Wr[15], h[15], r3);
            const float xh = brg + ((r0 + r1) + (r2 + r3));

            const float xc = fmaf(m, x - xh, xh);       // m*x + (1-m)*xh
            const float av = fabsf(x - xh) * m;         // loss contribution
            const float pre = fmaf(wx1, m, bias);
            const float gate = fmaf(wx0, xc, dot + pre);

            const float e = __builtin_amdgcn_exp2f(gate * cExp);
            const float sg = __builtin_amdgcn_rcpf(1.0f + e);
            const float act = fmaf(sMul, sg, sAdd);

            const float af = __shfl_xor(act, 16, 64);
            const float ag = __shfl_xor(act, 32, 64);
            const float ao = __shfl_xor(act, 48, 64);

            c = fmaf(af, c, act * ag);
            const float e2 = __builtin_amdgcn_exp2f(c * (-2.0f * L2E));
            const float th = fmaf(2.0f, __builtin_amdgcn_rcpf(1.0f + e2), -1.0f);
            const float ht = ao * th;

#pragma unroll
            for (int k = 0; k < NH; ++k) h[k] = rl(ht, k);

            if (ATOMIC) {
                if (lane == 0) atomicAdd(ab + t4 + s, av);
            }
            if (s == 0) { xi0 = xc; ai0 = av; } else if (s == 1) { xi1 = xc; ai1 = av; }
            else if (s == 2) { xi2 = xc; ai2 = av; } else { xi3 = xc; ai3 = av; }
        }
        if (ATOMIC) {
            const float iv = (lane == 0) ? xi0 : (lane == 1) ? xi1 : (lane == 2) ? xi2 : xi3;
            if (lane < 4) ib[t4 + lane] = iv;
        } else {
            // lanes 0-3 store imputations, lanes 4-7 store loss contributions
            const float v0 = (lane < 4) ? xi0 : ai0;
            const float v1 = (lane < 4) ? xi1 : ai1;
            const float v2 = (lane < 4) ? xi2 : ai2;
            const float v3 = (lane < 4) ? xi3 : ai3;
            const int q = lane & 3;
            const float v = (q == 0) ? v0 : (q == 1) ? v1 : (q == 2) ? v2 : v3;
            float* p = (lane < 4) ? (ib + t4 + q) : (ab + t4 + q);
            if (lane < 8) *p = v;
        }
        x0 = x1; m0 = m1; x1 = x2; m1 = m2; x2 = xpf; m2 = mpf;
    }
}

// ---------------- column-sum reduce: num_t / den_t ----------------
template <int ATOMIC>
__global__ void reduce_kernel(const float* __restrict__ masks,
                              const float* __restrict__ amt,
                              float* __restrict__ num_t,
                              float* __restrict__ den_t) {
    const int t = blockIdx.x * 256 + threadIdx.x;
    const int b0 = blockIdx.y * 32;
    float sd = 0.0f;
    for (int bb = b0; bb < b0 + 32; ++bb) sd += masks[(long)bb * NT + t];
    atomicAdd(den_t + t, sd);
    if (!ATOMIC) {
        float sn = 0.0f;
        for (int bb = b0; bb < b0 + 32; ++bb) sn += amt[(long)bb * NT + t];
        atomicAdd(num_t + t, sn);
    } else if (blockIdx.y == 0) {
        float sn = 0.0f;
        for (int r = 0; r < NREP; ++r) sn += amt[(long)r * NT + t];
        num_t[t] = sn;  // single writer
    }
}

// ---------------- loss finalize ----------------
__global__ void loss_kernel(const float* __restrict__ num_t, const float* __restrict__ den_t,
                            float* __restrict__ out) {
    const int tid = threadIdx.x;
    float s = 0.0f;
    for (int t = tid; t < NT; t += 256) s += num_t[t] / (den_t[t] + 1e-5f);
#pragma unroll
    for (int off = 32; off > 0; off >>= 1) s += __shfl_down(s, off, 64);
    __shared__ float red[4];
    if ((tid & 63) == 0) red[tid >> 6] = s;
    __syncthreads();
    if (tid == 0) out[0] = (red[0] + red[1] + red[2] + red[3]) / (float)NT;
}

extern "C" void kernel_launch(void* const* d_in, const int* in_sizes, int n_in,
                              void* d_out, int out_size, void* d_ws, size_t ws_size,
                              hipStream_t stream) {
    const float* values  = (const float*)d_in[0];
    const float* masks   = (const float*)d_in[1];
    const float* evals   = (const float*)d_in[2];
    const float* emask   = (const float*)d_in[3];
    const float* istrain = (const float*)d_in[4];
    const float* W_ih    = (const float*)d_in[5];
    const float* W_hh    = (const float*)d_in[6];
    const float* b_ih    = (const float*)d_in[7];
    const float* b_hh    = (const float*)d_in[8];
    const float* W_reg   = (const float*)d_in[9];
    const float* b_reg   = (const float*)d_in[10];

    float* out = (float*)d_out;
    float* ws = (float*)d_ws;
    float* num_t = ws;
    float* den_t = ws + NT;
    float* amt = ws + WS_AMT_OFF;

    const bool pathA = ws_size >= (size_t)(WS_AMT_OFF + (long)NB * NT) * 4;

    if (pathA) {
        copy_zero_kernel<<<1024, 256, 0, stream>>>(evals, emask, istrain, out, ws, WS_AMT_OFF);
        lstm_kernel<0><<<NB, 64, 0, stream>>>(values, masks, W_ih, W_hh, b_ih, b_hh,
                                              W_reg, b_reg, out + OFF_IMP, amt);
        reduce_kernel<0><<<dim3(NT / 256, 64), 256, 0, stream>>>(masks, amt, num_t, den_t);
    } else {
        copy_zero_kernel<<<1024, 256, 0, stream>>>(evals, emask, istrain, out, ws,
                                                   WS_AMT_OFF + NREP * NT);
        lstm_kernel<1><<<NB, 64, 0, stream>>>(values, masks, W_ih, W_hh, b_ih, b_hh,
                                              W_reg, b_reg, out + OFF_IMP, amt);
        reduce_kernel<1><<<dim3(NT / 256, 64), 256, 0, stream>>>(masks, amt, num_t, den_t);
    }
    loss_kernel<<<1, 256, 0, stream>>>(num_t, den_t, out);
}

// Round 4
// 557.189 us; speedup vs baseline: 5.9115x; 1.2894x over previous
//
#include <hip/hip_runtime.h>

#define NB 2048
#define NT 2048
#define NH 16

#define OFF_IMP   1L
#define OFF_TRAIN (1L + (long)NB * NT)
#define OFF_EVALS (OFF_TRAIN + NB)
#define OFF_EMASK (OFF_EVALS + (long)NB * NT)

// ws layout: num_t[NT] | den_t[NT] | amt[NB*NT] (path A)  or  rep[NREP*NT] (path B)
#define WS_AMT_OFF 4096
#define NREP 64

typedef float f2 __attribute__((ext_vector_type(2)));

// ---------------- copies + workspace zeroing ----------------
__global__ void copy_zero_kernel(const float* __restrict__ evals,
                                 const float* __restrict__ emask,
                                 const float* __restrict__ is_train,
                                 float* __restrict__ out,
                                 float* __restrict__ ws,
                                 int n_zero) {
    long gid = (long)blockIdx.x * blockDim.x + threadIdx.x;
    if (gid < n_zero) ws[gid] = 0.0f;
    const long n1 = (long)NB * NT;
    const long total = NB + 2 * n1;
    const long stride = (long)gridDim.x * blockDim.x;
    for (long i = gid; i < total; i += stride) {
        if (i < NB)            out[OFF_TRAIN + i] = is_train[i];
        else if (i < NB + n1)  out[OFF_EVALS + (i - NB)] = evals[i - NB];
        else                   out[OFF_EMASK + (i - NB - n1)] = emask[i - NB - n1];
    }
}

// ---------------- LSTM scan: gate-parallel, 64 lanes = 1 batch ----------------
// lane = gate*16 + j  (gate order: i, f, g, o — torch LSTMCell)

// One LSTM step. Uses enclosing vars: Wh2,Wr2,H2,c,hsh,lane,brg,bias,wx0,wx1,
// cExp,cT,sMul,sAdd,a32,a48.
#define STEP(xx, mm, XI, AI) do {                                              \
    f2 dA = H2[0] * Wh2[0];                                                    \
    f2 dB = H2[1] * Wh2[1];                                                    \
    dA = __builtin_elementwise_fma(H2[2], Wh2[2], dA);                         \
    dB = __builtin_elementwise_fma(H2[3], Wh2[3], dB);                         \
    dA = __builtin_elementwise_fma(H2[4], Wh2[4], dA);                         \
    dB = __builtin_elementwise_fma(H2[5], Wh2[5], dB);                         \
    dA = __builtin_elementwise_fma(H2[6], Wh2[6], dA);                         \
    dB = __builtin_elementwise_fma(H2[7], Wh2[7], dB);                         \
    f2 rA = H2[0] * Wr2[0];                                                    \
    f2 rB = H2[1] * Wr2[1];                                                    \
    rA = __builtin_elementwise_fma(H2[2], Wr2[2], rA);                         \
    rB = __builtin_elementwise_fma(H2[3], Wr2[3], rB);                         \
    rA = __builtin_elementwise_fma(H2[4], Wr2[4], rA);                         \
    rB = __builtin_elementwise_fma(H2[5], Wr2[5], rB);                         \
    rA = __builtin_elementwise_fma(H2[6], Wr2[6], rA);                         \
    rB = __builtin_elementwise_fma(H2[7], Wr2[7], rB);                         \
    const float dot = (dA.x + dA.y) + (dB.x + dB.y);                           \
    const float xh  = brg + ((rA.x + rA.y) + (rB.x + rB.y));                   \
    const float dxm = (xx) - xh;                                               \
    const float xc  = fmaf((mm), dxm, xh);                                     \
    const float av  = fabsf(dxm) * (mm);                                       \
    const float gate = fmaf(wx0, xc, dot + fmaf(wx1, (mm), bias));             \
    const float ex  = __builtin_amdgcn_exp2f(gate * cExp);                     \
    const float act = fmaf(sMul, __builtin_amdgcn_rcpf(1.0f + ex), sAdd);      \
    const int   ia  = __float_as_int(act);                                     \
    const float af  = __int_as_float(__builtin_amdgcn_ds_swizzle(ia, 0x401F)); \
    const float ag  = __int_as_float(__builtin_amdgcn_ds_bpermute(a32, ia));   \
    const float ao  = __int_as_float(__builtin_amdgcn_ds_bpermute(a48, ia));   \
    c = fmaf(af, c, act * ag);                                                 \
    const float e2 = __builtin_amdgcn_exp2f(c * cT);                           \
    const float th = fmaf(2.0f, __builtin_amdgcn_rcpf(1.0f + e2), -1.0f);      \
    const float ht = ao * th;                                                  \
    if (lane < NH) hsh[lane] = ht;                                             \
    _Pragma("unroll")                                                          \
    for (int k8 = 0; k8 < 8; ++k8) H2[k8] = *(const f2*)(hsh + 2 * k8);        \
    XI = xc; AI = av;                                                          \
} while (0)

#define QUAD(XV, MV, T4) do {                                                  \
    float xi0, xi1, xi2, xi3, ai0, ai1, ai2, ai3;                              \
    STEP(XV.x, MV.x, xi0, ai0); STEP(XV.y, MV.y, xi1, ai1);                    \
    STEP(XV.z, MV.z, xi2, ai2); STEP(XV.w, MV.w, xi3, ai3);                    \
    const float sx = (q == 1) ? xi1 : (q == 2) ? xi2 : (q == 3) ? xi3 : xi0;   \
    const float sa = (q == 1) ? ai1 : (q == 2) ? ai2 : (q == 3) ? ai3 : ai0;   \
    if (ATOMIC) {                                                              \
        if (lane == 0) {                                                       \
            atomicAdd(ab + (T4) + 0, ai0); atomicAdd(ab + (T4) + 1, ai1);      \
            atomicAdd(ab + (T4) + 2, ai2); atomicAdd(ab + (T4) + 3, ai3);      \
        }                                                                      \
        if (lane < 4) ib[(T4) + q] = sx;                                       \
    } else {                                                                   \
        if (lane < 8) pst[T4] = (lane < 4) ? sx : sa;                          \
    }                                                                          \
} while (0)

template <int ATOMIC>
__global__ __launch_bounds__(64, 2)
void lstm_kernel(const float* __restrict__ values,
                 const float* __restrict__ masks,
                 const float* __restrict__ W_ih,
                 const float* __restrict__ W_hh,
                 const float* __restrict__ b_ih,
                 const float* __restrict__ b_hh,
                 const float* __restrict__ W_reg,
                 const float* __restrict__ b_reg,
                 float* __restrict__ imp,   // out + OFF_IMP
                 float* __restrict__ amt) { // A: amt[NB*NT]; B: rep[NREP*NT]
    const int lane = threadIdx.x;          // 0..63
    const int G = lane >> 4;               // gate index
    const int q = lane & 3;
    const long b = blockIdx.x;             // one batch per block/wave

    f2 Wh2[8], Wr2[8];
#pragma unroll
    for (int k = 0; k < 8; ++k) {
        Wh2[k] = *(const f2*)(W_hh + lane * NH + 2 * k);
        Wr2[k] = *(const f2*)(W_reg + 2 * k);
    }
    const float wx0 = W_ih[lane * 2 + 0];
    const float wx1 = W_ih[lane * 2 + 1];
    const float bias = b_ih[lane] + b_hh[lane];
    const float brg = b_reg[0];

    const float L2E = 1.4426950408889634f;
    const float cExp = (G == 2) ? -2.0f * L2E : -L2E;  // tanh for gate g, sigmoid else
    const float cT   = -2.0f * L2E;
    const float sMul = (G == 2) ? 2.0f : 1.0f;
    const float sAdd = (G == 2) ? -1.0f : 0.0f;

    // hoisted cross-lane gather addresses (xor32 / xor48)
    const int a32 = (lane ^ 32) << 2;
    const int a48 = (lane ^ 48) << 2;

    f2 H2[8];
#pragma unroll
    for (int k = 0; k < 8; ++k) H2[k] = (f2){0.0f, 0.0f};
    float c = 0.0f;

    __shared__ __align__(16) float hsh[NH];

    const float* vb = values + b * NT;
    const float* mb = masks + b * NT;
    float* ib = imp + b * NT;
    float* ab = ATOMIC ? (amt + (long)(b & (NREP - 1)) * NT) : (amt + b * NT);
    // lanes 0-3 -> imputation column q, lanes 4-7 -> loss column q
    float* pst = ((lane < 4) ? ib : ab) + q;

    // 4 static prefetch buffers, 16-step unrolled body -> no rotation movs
    float4 xA = *(const float4*)(vb + 0),  mA = *(const float4*)(mb + 0);
    float4 xB = *(const float4*)(vb + 4),  mB = *(const float4*)(mb + 4);
    float4 xC = *(const float4*)(vb + 8),  mC = *(const float4*)(mb + 8);
    float4 xD = *(const float4*)(vb + 12), mD = *(const float4*)(mb + 12);

    for (int t = 0; t < NT; t += 16) {
        QUAD(xA, mA, t + 0);
        QUAD(xB, mB, t + 4);
        {
            const int tn = (t + 16) & (NT - 1);  // wraps harmlessly on last iter
            xA = *(const float4*)(vb + tn);      mA = *(const float4*)(mb + tn);
            xB = *(const float4*)(vb + tn + 4);  mB = *(const float4*)(mb + tn + 4);
        }
        QUAD(xC, mC, t + 8);
        QUAD(xD, mD, t + 12);
        {
            const int tn = (t + 24) & (NT - 1);
            xC = *(const float4*)(vb + tn);      mC = *(const float4*)(mb + tn);
            xD = *(const float4*)(vb + tn + 4);  mD = *(const float4*)(mb + tn + 4);
        }
    }
}

// ---------------- column-sum reduce: num_t / den_t ----------------
template <int ATOMIC>
__global__ void reduce_kernel(const float* __restrict__ masks,
                              const float* __restrict__ amt,
                              float* __restrict__ num_t,
                              float* __restrict__ den_t) {
    const int t = blockIdx.x * 256 + threadIdx.x;
    const int b0 = blockIdx.y * 32;
    float sd = 0.0f;
    for (int bb = b0; bb < b0 + 32; ++bb) sd += masks[(long)bb * NT + t];
    atomicAdd(den_t + t, sd);
    if (!ATOMIC) {
        float sn = 0.0f;
        for (int bb = b0; bb < b0 + 32; ++bb) sn += amt[(long)bb * NT + t];
        atomicAdd(num_t + t, sn);
    } else if (blockIdx.y == 0) {
        float sn = 0.0f;
        for (int r = 0; r < NREP; ++r) sn += amt[(long)r * NT + t];
        num_t[t] = sn;  // single writer
    }
}

// ---------------- loss finalize ----------------
__global__ void loss_kernel(const float* __restrict__ num_t, const float* __restrict__ den_t,
                            float* __restrict__ out) {
    const int tid = threadIdx.x;
    float s = 0.0f;
    for (int t = tid; t < NT; t += 256) s += num_t[t] / (den_t[t] + 1e-5f);
#pragma unroll
    for (int off = 32; off > 0; off >>= 1) s += __shfl_down(s, off, 64);
    __shared__ float red[4];
    if ((tid & 63) == 0) red[tid >> 6] = s;
    __syncthreads();
    if (tid == 0) out[0] = (red[0] + red[1] + red[2] + red[3]) / (float)NT;
}

extern "C" void kernel_launch(void* const* d_in, const int* in_sizes, int n_in,
                              void* d_out, int out_size, void* d_ws, size_t ws_size,
                              hipStream_t stream) {
    const float* values  = (const float*)d_in[0];
    const float* masks   = (const float*)d_in[1];
    const float* evals   = (const float*)d_in[2];
    const float* emask   = (const float*)d_in[3];
    const float* istrain = (const float*)d_in[4];
    const float* W_ih    = (const float*)d_in[5];
    const float* W_hh    = (const float*)d_in[6];
    const float* b_ih    = (const float*)d_in[7];
    const float* b_hh    = (const float*)d_in[8];
    const float* W_reg   = (const float*)d_in[9];
    const float* b_reg   = (const float*)d_in[10];

    float* out = (float*)d_out;
    float* ws = (float*)d_ws;
    float* num_t = ws;
    float* den_t = ws + NT;
    float* amt = ws + WS_AMT_OFF;

    const bool pathA = ws_size >= (size_t)(WS_AMT_OFF + (long)NB * NT) * 4;

    if (pathA) {
        copy_zero_kernel<<<1024, 256, 0, stream>>>(evals, emask, istrain, out, ws, WS_AMT_OFF);
        lstm_kernel<0><<<NB, 64, 0, stream>>>(values, masks, W_ih, W_hh, b_ih, b_hh,
                                              W_reg, b_reg, out + OFF_IMP, amt);
        reduce_kernel<0><<<dim3(NT / 256, 64), 256, 0, stream>>>(masks, amt, num_t, den_t);
    } else {
        copy_zero_kernel<<<1024, 256, 0, stream>>>(evals, emask, istrain, out, ws,
                                                   WS_AMT_OFF + NREP * NT);
        lstm_kernel<1><<<NB, 64, 0, stream>>>(values, masks, W_ih, W_hh, b_ih, b_hh,
                                              W_reg, b_reg, out + OFF_IMP, amt);
        reduce_kernel<1><<<dim3(NT / 256, 64), 256, 0, stream>>>(masks, amt, num_t, den_t);
    }
    loss_kernel<<<1, 256, 0, stream>>>(num_t, den_t, out);
}